// Round 1
// baseline (240.580 us; speedup 1.0000x reference)
//
#include <hip/hip_runtime.h>
#include <hip/hip_fp16.h>
#include <stdint.h>

#define M_DIM 64
#define K_DIM 8192
#define N_DIM 28672
#define QGROUP 128

typedef __attribute__((ext_vector_type(4))) float floatx4;
typedef __attribute__((ext_vector_type(8))) _Float16 halfx8;
typedef __attribute__((ext_vector_type(4))) uint32_t uintx4;

// bit_cast via memcpy (works for non-trivially-copyable HIP types)
template <typename T, typename F>
__device__ __forceinline__ T bc(F f) {
  static_assert(sizeof(T) == sizeof(F), "size mismatch");
  T t;
  __builtin_memcpy(&t, &f, sizeof(T));
  return t;
}

// p = two fp16 lanes holding (1024+nib); returns two fp16 of (nib-8)*s
// (1024+nib and 1032 are fp16-exact, same binade -> sub exact; mul RNE =
// exactly the reference's fp16 multiply)
__device__ __forceinline__ uint32_t dq_pair(uint32_t p, uint32_t s2bits) {
  __half2 v = bc<__half2>(p);
  __half2 z = bc<__half2>(0x64086408u);  // (1032, 1032)
  __half2 s = bc<__half2>(s2bits);
  return bc<uint32_t>(__hmul2(__hsub2(v, z), s));
}

// one packed dword (8 nibbles, consecutive k) -> B fragment (8 fp16) for one n
__device__ __forceinline__ halfx8 dequant8(uint32_t q, uint32_t s2bits) {
  const uint32_t MG = 0x64006400u;  // fp16(1024) in both halves
  uint32_t p01 = ((q & 0x0000000Fu) | ((q << 12) & 0x000F0000u)) | MG;
  uint32_t p23 = (((q >> 8) & 0x0000000Fu) | ((q << 4) & 0x000F0000u)) | MG;
  uint32_t p45 = (((q >> 16) & 0x0000000Fu) | ((q >> 4) & 0x000F0000u)) | MG;
  uint32_t p67 = (((q >> 24) & 0x0000000Fu) | ((q >> 12) & 0x000F0000u)) | MG;
  uintx4 r;
  r.x = dq_pair(p01, s2bits);
  r.y = dq_pair(p23, s2bits);
  r.z = dq_pair(p45, s2bits);
  r.w = dq_pair(p67, s2bits);
  return bc<halfx8>(r);
}

// A (fp32, 64x8192, fp16-exact) -> fragment-ordered fp16 pack so the main
// kernel's A-fragment loads are lane-consecutive global_load_dwordx4.
// Apack[((t*4+mf)*64 + l)*8 + j] = (f16) A[(l&15)+16*mf][32*t + 8*(l>>4) + j]
// (identical element mapping to the old LDS staging, verified against it)
__global__ __launch_bounds__(256) void pack_a(const float* __restrict__ A,
                                              _Float16* __restrict__ Apack) {
  const int g = (int)blockIdx.x * 256 + (int)threadIdx.x;  // 0 .. 65535
  const int l = g & 63;
  const int mf = (g >> 6) & 3;
  const int t = g >> 8;
  const int row = (l & 15) + 16 * mf;
  const int k0 = 32 * t + 8 * (l >> 4);
  const float* src = A + (size_t)row * K_DIM + k0;
  floatx4 a0 = *(const floatx4*)src;
  floatx4 a1 = *(const floatx4*)(src + 4);
  halfx8 hv;
#pragma unroll
  for (int j = 0; j < 4; ++j) hv[j] = (_Float16)a0[j];
#pragma unroll
  for (int j = 0; j < 4; ++j) hv[4 + j] = (_Float16)a1[j];
  *(halfx8*)(Apack + (size_t)g * 8) = hv;
}

// Block: 256 threads = 4 fully INDEPENDENT waves (no LDS, no barriers).
// Each wave owns a 64m x 64n output tile over KSLICE of K.
// A fragments come from the fragment-ordered Apack (1 MB, L2-resident,
// coalesced dwordx4); B dequanted in registers from qweight; q prefetched
// 2 steps deep to cover HBM latency.
template <int KSLICE, bool SPLIT, bool PACKED>
__global__ __launch_bounds__(256, 4) void wq_mfma(
    const float* __restrict__ A,        // fp32 raw (only used if !PACKED)
    const _Float16* __restrict__ Apack, // fragment-ordered fp16
    const int* __restrict__ qweight,    // int32, K/8 x N
    const float* __restrict__ scales,   // fp32, K/128 x N (fp16-exact)
    const float* __restrict__ bias,     // fp32, N (fp16-exact)
    float* __restrict__ part,           // KSPLIT x M x N (fp32)
    float* __restrict__ out) {          // fp32, M x N
  constexpr int STEPS = KSLICE / 32;
  constexpr int GROUPS = KSLICE / QGROUP;

  const int tid = (int)threadIdx.x;
  const int w = tid >> 6;
  const int l = tid & 63;
  const int l15 = l & 15;
  const int l4 = l >> 4;
  const int nb = (int)blockIdx.x * 256 + w * 64;
  const int kb = (int)blockIdx.y * KSLICE;
  const int ncol = nb + 4 * l15;  // lane's first n (4 interleaved via d)

  const int* qptr = qweight + (size_t)((kb >> 3) + l4) * N_DIM + ncol;
  const float* sptr = scales + (size_t)(kb / QGROUP) * N_DIM + ncol;
  // per-step stride 2048 halves (4 KB); mf at +512 halves (imm offset)
  const _Float16* apt = Apack + ((size_t)(kb >> 5) * 256 + l) * 8;
  // raw-A fallback base (row l15, k = kb + 8*l4); mf at +16 rows
  const float* araw = A + (size_t)l15 * K_DIM + (kb + 8 * l4);

  floatx4 acc[4][4];
#pragma unroll
  for (int i = 0; i < 4; ++i)
#pragma unroll
    for (int j = 0; j < 4; ++j) acc[i][j] = (floatx4)(0.0f);

  // q prefetch: 2 steps in flight
  uintx4 q0 = *(const uintx4*)qptr;
  qptr += 4 * (size_t)N_DIM;
  uintx4 q1 = (STEPS > 1) ? *(const uintx4*)qptr : q0;
  qptr += 4 * (size_t)N_DIM;
  floatx4 scv = *(const floatx4*)sptr;
  sptr += N_DIM;

  for (int g = 0; g < GROUPS; ++g) {
    uint32_t s2b[4];
#pragma unroll
    for (int d = 0; d < 4; ++d) {
      unsigned short sb = bc<unsigned short>((_Float16)scv[d]);  // exact
      s2b[d] = (uint32_t)sb * 0x10001u;                          // fp16x2 splat
    }
    floatx4 scn = scv;
    if (g + 1 < GROUPS) scn = *(const floatx4*)sptr;
    sptr += N_DIM;
#pragma unroll
    for (int tt = 0; tt < 4; ++tt) {
      const int t = g * 4 + tt;
      // A fragments first (L1/L2 hits; waited with qn still outstanding)
      halfx8 afr[4];
      if constexpr (PACKED) {
#pragma unroll
        for (int mf = 0; mf < 4; ++mf)
          afr[mf] = *(const halfx8*)(apt + mf * 512);
        apt += 2048;
      } else {
#pragma unroll
        for (int mf = 0; mf < 4; ++mf) {
          const float* s0 = araw + (size_t)mf * 16 * K_DIM + (size_t)t * 32;
          floatx4 a0 = *(const floatx4*)s0;
          floatx4 a1 = *(const floatx4*)(s0 + 4);
#pragma unroll
          for (int j = 0; j < 4; ++j) afr[mf][j] = (_Float16)a0[j];
#pragma unroll
          for (int j = 0; j < 4; ++j) afr[mf][4 + j] = (_Float16)a1[j];
        }
      }
      // q prefetch for step t+2 (HBM latency covered by 2-step lead)
      uintx4 qn = q1;
      if (t + 2 < STEPS) qn = *(const uintx4*)qptr;
      qptr += 4 * (size_t)N_DIM;

      // d-major: keep the B fragment's live range short (4 VGPRs)
#pragma unroll
      for (int d = 0; d < 4; ++d) {
        halfx8 b = dequant8(q0[d], s2b[d]);
#pragma unroll
        for (int mf = 0; mf < 4; ++mf)
          acc[mf][d] = __builtin_amdgcn_mfma_f32_16x16x32_f16(afr[mf], b,
                                                              acc[mf][d], 0, 0, 0);
      }
      q0 = q1;
      q1 = qn;
    }
    scv = scn;
  }

  // Epilogue. C layout: row = 4*l4 + reg (+16*mf), col = l&15; fragment d's
  // col c is global n = nb + 4*c + d -> 4 fragments at fixed (mf, r) are 4
  // consecutive n. Output is FP32.
  if (SPLIT) {
    float* pbase = part + (size_t)blockIdx.y * ((size_t)M_DIM * N_DIM);
#pragma unroll
    for (int mf = 0; mf < 4; ++mf) {
#pragma unroll
      for (int r = 0; r < 4; ++r) {
        const int m = mf * 16 + l4 * 4 + r;
        floatx4 v = {acc[mf][0][r], acc[mf][1][r], acc[mf][2][r], acc[mf][3][r]};
        *(floatx4*)(pbase + (size_t)m * N_DIM + ncol) = v;
      }
    }
  } else {
    floatx4 bb = *(const floatx4*)(bias + ncol);
#pragma unroll
    for (int mf = 0; mf < 4; ++mf) {
#pragma unroll
      for (int r = 0; r < 4; ++r) {
        const int m = mf * 16 + l4 * 4 + r;
        floatx4 v = {acc[mf][0][r] + bb.x, acc[mf][1][r] + bb.y,
                     acc[mf][2][r] + bb.z, acc[mf][3][r] + bb.w};
        *(floatx4*)(out + (size_t)m * N_DIM + ncol) = v;
      }
    }
  }
}

// Sum KS fp32 partials, add fp32 bias, emit fp32.
template <int KS>
__global__ __launch_bounds__(256) void wq_reduce(const float* __restrict__ part,
                                                 const float* __restrict__ bias,
                                                 float* __restrict__ out) {
  const int idx = (int)blockIdx.x * 256 + (int)threadIdx.x;  // over M*N/4
  const int m = idx / (N_DIM / 4);
  const int n = (idx - m * (N_DIM / 4)) * 4;
  floatx4 s = (floatx4)(0.0f);
#pragma unroll
  for (int p = 0; p < KS; ++p)
    s += *(const floatx4*)(part + ((size_t)p * M_DIM + m) * N_DIM + n);
  floatx4 bb = *(const floatx4*)(bias + n);
  s += bb;
  *(floatx4*)(out + (size_t)m * N_DIM + n) = s;
}

extern "C" void kernel_launch(void* const* d_in, const int* in_sizes, int n_in,
                              void* d_out, int out_size, void* d_ws, size_t ws_size,
                              hipStream_t stream) {
  const float* A = (const float*)d_in[0];    // fp32 (64x8192), fp16-exact
  const int* qw = (const int*)d_in[1];       // int32 (1024x28672)
  const float* sc = (const float*)d_in[2];   // fp32 (64x28672), fp16-exact
  const float* bi = (const float*)d_in[3];   // fp32 (28672), fp16-exact
  float* out = (float*)d_out;                // fp32 (64x28672)

  char* ws = (char*)d_ws;
  const size_t packB = (size_t)M_DIM * K_DIM * sizeof(_Float16);  // 1 MiB
  const size_t mnB = (size_t)M_DIM * N_DIM * sizeof(float);       // 7.34 MB
  _Float16* Apack = (_Float16*)ws;
  float* part = (float*)(ws + packB);

  const int nblk = N_DIM / 256;        // 112
  const int rblk = (M_DIM * N_DIM / 4) / 256;  // 1792

  if (ws_size >= packB + 8 * mnB) {
    pack_a<<<256, 256, 0, stream>>>(A, Apack);
    wq_mfma<K_DIM / 8, true, true><<<dim3(nblk, 8), 256, 0, stream>>>(
        A, Apack, qw, sc, bi, part, out);
    wq_reduce<8><<<rblk, 256, 0, stream>>>(part, bi, out);
  } else if (ws_size >= packB + 4 * mnB) {
    pack_a<<<256, 256, 0, stream>>>(A, Apack);
    wq_mfma<K_DIM / 4, true, true><<<dim3(nblk, 4), 256, 0, stream>>>(
        A, Apack, qw, sc, bi, part, out);
    wq_reduce<4><<<rblk, 256, 0, stream>>>(part, bi, out);
  } else if (ws_size >= packB + 2 * mnB) {
    pack_a<<<256, 256, 0, stream>>>(A, Apack);
    wq_mfma<K_DIM / 2, true, true><<<dim3(nblk, 2), 256, 0, stream>>>(
        A, Apack, qw, sc, bi, part, out);
    wq_reduce<2><<<rblk, 256, 0, stream>>>(part, bi, out);
  } else if (ws_size >= packB) {
    pack_a<<<256, 256, 0, stream>>>(A, Apack);
    wq_mfma<K_DIM, false, true><<<dim3(nblk, 1), 256, 0, stream>>>(
        A, Apack, qw, sc, bi, part, out);
  } else {
    wq_mfma<K_DIM, false, false><<<dim3(nblk, 1), 256, 0, stream>>>(
        A, (const _Float16*)nullptr, qw, sc, bi, part, out);
  }
}

// Round 2
// 221.202 us; speedup vs baseline: 1.0876x; 1.0876x over previous
//
#include <hip/hip_runtime.h>
#include <hip/hip_fp16.h>
#include <stdint.h>

#define M_DIM 64
#define K_DIM 8192
#define N_DIM 28672
#define QGROUP 128

typedef __attribute__((ext_vector_type(4))) float floatx4;
typedef __attribute__((ext_vector_type(8))) _Float16 halfx8;
typedef __attribute__((ext_vector_type(4))) uint32_t uintx4;

// bit_cast via memcpy (works for non-trivially-copyable HIP types)
template <typename T, typename F>
__device__ __forceinline__ T bc(F f) {
  static_assert(sizeof(T) == sizeof(F), "size mismatch");
  T t;
  __builtin_memcpy(&t, &f, sizeof(T));
  return t;
}

// p = two fp16 lanes holding (1024+nib); returns two fp16 of (nib-8)*s
// (1024+nib and 1032 are fp16-exact, same binade -> sub exact; mul RNE =
// exactly the reference's fp16 multiply)
__device__ __forceinline__ uint32_t dq_pair(uint32_t p, uint32_t s2bits) {
  __half2 v = bc<__half2>(p);
  __half2 z = bc<__half2>(0x64086408u);  // (1032, 1032)
  __half2 s = bc<__half2>(s2bits);
  return bc<uint32_t>(__hmul2(__hsub2(v, z), s));
}

// one packed dword (8 nibbles, consecutive k) -> B fragment (8 fp16) for one n
__device__ __forceinline__ halfx8 dequant8(uint32_t q, uint32_t s2bits) {
  const uint32_t MG = 0x64006400u;  // fp16(1024) in both halves
  uint32_t p01 = ((q & 0x0000000Fu) | ((q << 12) & 0x000F0000u)) | MG;
  uint32_t p23 = (((q >> 8) & 0x0000000Fu) | ((q << 4) & 0x000F0000u)) | MG;
  uint32_t p45 = (((q >> 16) & 0x0000000Fu) | ((q >> 4) & 0x000F0000u)) | MG;
  uint32_t p67 = (((q >> 24) & 0x0000000Fu) | ((q >> 12) & 0x000F0000u)) | MG;
  uintx4 r;
  r.x = dq_pair(p01, s2bits);
  r.y = dq_pair(p23, s2bits);
  r.z = dq_pair(p45, s2bits);
  r.w = dq_pair(p67, s2bits);
  return bc<halfx8>(r);
}

// A (fp32, 64x8192, fp16-exact) -> fragment-ordered fp16 pack so the main
// kernel's A-fragment loads are lane-consecutive global_load_dwordx4.
// Apack[((t*4+mf)*64 + l)*8 + j] = (f16) A[(l&15)+16*mf][32*t + 8*(l>>4) + j]
__global__ __launch_bounds__(256) void pack_a(const float* __restrict__ A,
                                              _Float16* __restrict__ Apack) {
  const int g = (int)blockIdx.x * 256 + (int)threadIdx.x;  // 0 .. 65535
  const int l = g & 63;
  const int mf = (g >> 6) & 3;
  const int t = g >> 8;
  const int row = (l & 15) + 16 * mf;
  const int k0 = 32 * t + 8 * (l >> 4);
  const float* src = A + (size_t)row * K_DIM + k0;
  floatx4 a0 = *(const floatx4*)src;
  floatx4 a1 = *(const floatx4*)(src + 4);
  halfx8 hv;
#pragma unroll
  for (int j = 0; j < 4; ++j) hv[j] = (_Float16)a0[j];
#pragma unroll
  for (int j = 0; j < 4; ++j) hv[4 + j] = (_Float16)a1[j];
  *(halfx8*)(Apack + (size_t)g * 8) = hv;
}

// ONE WAVE PER BLOCK (64 threads). Wave owns a 64m x 64n output tile over
// KSLICE of K. Grid (N/64, KSPLIT) = 448*4 = 1792 blocks -> exactly 7
// blocks/CU, perfectly even. Latency hidden by ILP:
//   - A fragments (L2-resident Apack) software-pipelined 1 step ahead
//   - qweight (HBM stream) prefetched 3 steps ahead (~900cy / ~300cy step)
// No LDS, no barriers. launch_bounds(64,2) -> 256-VGPR budget so the
// pipeline registers actually materialize.
template <int KSLICE, bool SPLIT, bool PACKED>
__global__ __launch_bounds__(64, 2) void wq_mfma(
    const float* __restrict__ A,        // fp32 raw (only used if !PACKED)
    const _Float16* __restrict__ Apack, // fragment-ordered fp16
    const int* __restrict__ qweight,    // int32, K/8 x N
    const float* __restrict__ scales,   // fp32, K/128 x N (fp16-exact)
    const float* __restrict__ bias,     // fp32, N (fp16-exact)
    float* __restrict__ part,           // KSPLIT x M x N (fp32)
    float* __restrict__ out) {          // fp32, M x N
  constexpr int STEPS = KSLICE / 32;
  constexpr int GROUPS = KSLICE / QGROUP;

  const int l = (int)threadIdx.x & 63;
  const int l15 = l & 15;
  const int l4 = l >> 4;
  const int nb = (int)blockIdx.x * 64;
  const int kb = (int)blockIdx.y * KSLICE;
  const int ncol = nb + 4 * l15;  // lane's first n (4 interleaved via d)

  const int* qptr = qweight + (size_t)((kb >> 3) + l4) * N_DIM + ncol;
  const float* sptr = scales + (size_t)(kb / QGROUP) * N_DIM + ncol;
  // per-step stride 2048 halves (4 KB); mf at +512 halves (imm offset)
  const _Float16* apt = Apack + ((size_t)(kb >> 5) * 256 + l) * 8;
  // raw-A fallback base (row l15, k = kb + 8*l4); mf at +16 rows
  const float* araw = A + (size_t)l15 * K_DIM + (kb + 8 * l4);

  floatx4 acc[4][4];
#pragma unroll
  for (int i = 0; i < 4; ++i)
#pragma unroll
    for (int j = 0; j < 4; ++j) acc[i][j] = (floatx4)(0.0f);

  // q prefetch: 3 steps in flight
  uintx4 q0 = *(const uintx4*)qptr;
  qptr += 4 * (size_t)N_DIM;
  uintx4 q1 = (STEPS > 1) ? *(const uintx4*)qptr : q0;
  qptr += 4 * (size_t)N_DIM;
  uintx4 q2 = (STEPS > 2) ? *(const uintx4*)qptr : q1;
  qptr += 4 * (size_t)N_DIM;
  floatx4 scv = *(const floatx4*)sptr;
  sptr += N_DIM;

  // A fragments for step 0
  halfx8 afr[4];
  if constexpr (PACKED) {
#pragma unroll
    for (int mf = 0; mf < 4; ++mf) afr[mf] = *(const halfx8*)(apt + mf * 512);
    apt += 2048;
  } else {
#pragma unroll
    for (int mf = 0; mf < 4; ++mf) {
      const float* s0 = araw + (size_t)mf * 16 * K_DIM;
      floatx4 a0 = *(const floatx4*)s0;
      floatx4 a1 = *(const floatx4*)(s0 + 4);
#pragma unroll
      for (int j = 0; j < 4; ++j) afr[mf][j] = (_Float16)a0[j];
#pragma unroll
      for (int j = 0; j < 4; ++j) afr[mf][4 + j] = (_Float16)a1[j];
    }
  }

  for (int g = 0; g < GROUPS; ++g) {
    uint32_t s2b[4];
#pragma unroll
    for (int d = 0; d < 4; ++d) {
      unsigned short sb = bc<unsigned short>((_Float16)scv[d]);  // exact
      s2b[d] = (uint32_t)sb * 0x10001u;                          // fp16x2 splat
    }
    floatx4 scn = scv;
    if (g + 1 < GROUPS) scn = *(const floatx4*)sptr;
    sptr += N_DIM;
#pragma unroll
    for (int tt = 0; tt < 4; ++tt) {
      const int t = g * 4 + tt;
      // A fragment prefetch for step t+1 (L2 hit, hidden under MFMA burst)
      halfx8 afrN[4];
      const bool do_a = (t + 1 < STEPS);
      if constexpr (PACKED) {
        if (do_a) {
#pragma unroll
          for (int mf = 0; mf < 4; ++mf)
            afrN[mf] = *(const halfx8*)(apt + mf * 512);
        }
        apt += 2048;
      } else {
        if (do_a) {
#pragma unroll
          for (int mf = 0; mf < 4; ++mf) {
            const float* s0 = araw + (size_t)mf * 16 * K_DIM + (size_t)(t + 1) * 32;
            floatx4 a0 = *(const floatx4*)s0;
            floatx4 a1 = *(const floatx4*)(s0 + 4);
#pragma unroll
            for (int j = 0; j < 4; ++j) afrN[mf][j] = (_Float16)a0[j];
#pragma unroll
            for (int j = 0; j < 4; ++j) afrN[mf][4 + j] = (_Float16)a1[j];
          }
        }
      }
      // q prefetch for step t+3 (HBM latency covered by 3-step lead)
      uintx4 qn = q2;
      if (t + 3 < STEPS) qn = *(const uintx4*)qptr;
      qptr += 4 * (size_t)N_DIM;

      // d-major: keep the B fragment's live range short (4 VGPRs)
#pragma unroll
      for (int d = 0; d < 4; ++d) {
        halfx8 b = dequant8(q0[d], s2b[d]);
#pragma unroll
        for (int mf = 0; mf < 4; ++mf)
          acc[mf][d] = __builtin_amdgcn_mfma_f32_16x16x32_f16(afr[mf], b,
                                                              acc[mf][d], 0, 0, 0);
      }
      if (do_a) {
#pragma unroll
        for (int mf = 0; mf < 4; ++mf) afr[mf] = afrN[mf];
      }
      q0 = q1;
      q1 = q2;
      q2 = qn;
    }
    scv = scn;
  }

  // Epilogue. C layout: row = 4*l4 + reg (+16*mf), col = l&15; fragment d's
  // col c is global n = nb + 4*c + d -> 4 fragments at fixed (mf, r) are 4
  // consecutive n. Output is FP32.
  if (SPLIT) {
    float* pbase = part + (size_t)blockIdx.y * ((size_t)M_DIM * N_DIM);
#pragma unroll
    for (int mf = 0; mf < 4; ++mf) {
#pragma unroll
      for (int r = 0; r < 4; ++r) {
        const int m = mf * 16 + l4 * 4 + r;
        floatx4 v = {acc[mf][0][r], acc[mf][1][r], acc[mf][2][r], acc[mf][3][r]};
        *(floatx4*)(pbase + (size_t)m * N_DIM + ncol) = v;
      }
    }
  } else {
    floatx4 bb = *(const floatx4*)(bias + ncol);
#pragma unroll
    for (int mf = 0; mf < 4; ++mf) {
#pragma unroll
      for (int r = 0; r < 4; ++r) {
        const int m = mf * 16 + l4 * 4 + r;
        floatx4 v = {acc[mf][0][r] + bb.x, acc[mf][1][r] + bb.y,
                     acc[mf][2][r] + bb.z, acc[mf][3][r] + bb.w};
        *(floatx4*)(out + (size_t)m * N_DIM + ncol) = v;
      }
    }
  }
}

// Sum KS fp32 partials, add fp32 bias, emit fp32.
template <int KS>
__global__ __launch_bounds__(256) void wq_reduce(const float* __restrict__ part,
                                                 const float* __restrict__ bias,
                                                 float* __restrict__ out) {
  const int idx = (int)blockIdx.x * 256 + (int)threadIdx.x;  // over M*N/4
  const int m = idx / (N_DIM / 4);
  const int n = (idx - m * (N_DIM / 4)) * 4;
  floatx4 s = (floatx4)(0.0f);
#pragma unroll
  for (int p = 0; p < KS; ++p)
    s += *(const floatx4*)(part + ((size_t)p * M_DIM + m) * N_DIM + n);
  floatx4 bb = *(const floatx4*)(bias + n);
  s += bb;
  *(floatx4*)(out + (size_t)m * N_DIM + n) = s;
}

extern "C" void kernel_launch(void* const* d_in, const int* in_sizes, int n_in,
                              void* d_out, int out_size, void* d_ws, size_t ws_size,
                              hipStream_t stream) {
  const float* A = (const float*)d_in[0];    // fp32 (64x8192), fp16-exact
  const int* qw = (const int*)d_in[1];       // int32 (1024x28672)
  const float* sc = (const float*)d_in[2];   // fp32 (64x28672), fp16-exact
  const float* bi = (const float*)d_in[3];   // fp32 (28672), fp16-exact
  float* out = (float*)d_out;                // fp32 (64x28672)

  char* ws = (char*)d_ws;
  const size_t packB = (size_t)M_DIM * K_DIM * sizeof(_Float16);  // 1 MiB
  const size_t mnB = (size_t)M_DIM * N_DIM * sizeof(float);       // 7.34 MB
  _Float16* Apack = (_Float16*)ws;
  float* part = (float*)(ws + packB);

  const int nblk = N_DIM / 64;                 // 448 (1-wave blocks)
  const int rblk = (M_DIM * N_DIM / 4) / 256;  // 1792

  if (ws_size >= packB + 4 * mnB) {
    pack_a<<<256, 256, 0, stream>>>(A, Apack);
    wq_mfma<K_DIM / 4, true, true><<<dim3(nblk, 4), 64, 0, stream>>>(
        A, Apack, qw, sc, bi, part, out);
    wq_reduce<4><<<rblk, 256, 0, stream>>>(part, bi, out);
  } else if (ws_size >= packB + 2 * mnB) {
    pack_a<<<256, 256, 0, stream>>>(A, Apack);
    wq_mfma<K_DIM / 2, true, true><<<dim3(nblk, 2), 64, 0, stream>>>(
        A, Apack, qw, sc, bi, part, out);
    wq_reduce<2><<<rblk, 256, 0, stream>>>(part, bi, out);
  } else if (ws_size >= packB) {
    pack_a<<<256, 256, 0, stream>>>(A, Apack);
    wq_mfma<K_DIM, false, true><<<dim3(nblk, 1), 64, 0, stream>>>(
        A, Apack, qw, sc, bi, part, out);
  } else {
    wq_mfma<K_DIM, false, false><<<dim3(nblk, 1), 64, 0, stream>>>(
        A, (const _Float16*)nullptr, qw, sc, bi, part, out);
  }
}